// Round 3
// baseline (251.012 us; speedup 1.0000x reference)
//
#include <hip/hip_runtime.h>
#include <hip/hip_cooperative_groups.h>

namespace cg = cooperative_groups;

typedef _Float16 f16;
typedef _Float16 half8 __attribute__((ext_vector_type(8)));
typedef float f32x4 __attribute__((ext_vector_type(4)));
typedef float f32x16 __attribute__((ext_vector_type(16)));
typedef unsigned u32x4 __attribute__((ext_vector_type(4)));

#define LDW 72  // padded LDS leading dim (f16): 144B row stride

// ================= fused cooperative kernel: 256 blocks x 256 threads (1 block/CU) ==========
// P0: stage wT(w1..w3)+biases to LDS; per-block BN partial sums (64 rows/block); block0 zeroes sums
// P1: atomic-reduce partials into sums
// P2: BN apply + QKV projections (64 rows/block, 4 waves)
// P3: streaming attention, swapped-QK^T 32x32x16, in-register softmax, split-K=8,
//     two sequential 256-row Q halves per block (same K/V tiles, L2-resident re-stream)
// P4: weighted merge of normalized partials + W4 projection + bias + residual (64 rows/block)
__global__ __launch_bounds__(256, 2) void k_fused(
    const float* __restrict__ x,
    const float* __restrict__ w1, const float* __restrict__ w2, const float* __restrict__ w3,
    const float* __restrict__ w4,
    const float* __restrict__ b1, const float* __restrict__ b2, const float* __restrict__ b3,
    const float* __restrict__ b4,
    const float* __restrict__ gamma, const float* __restrict__ beta,
    float* __restrict__ sums,
    f16* __restrict__ Q, f16* __restrict__ Kx, f16* __restrict__ Vt,
    f16* __restrict__ Oph, float* __restrict__ lw,
    float* __restrict__ out)
{
    __shared__ char smem[37888] __attribute__((aligned(16)));
    cg::grid_group grid = cg::this_grid();
    int t = threadIdx.x;
    int bid = blockIdx.x;

    // ---------------- P0 ----------------
    {
        f16*  wT  = (f16*)smem;                  // 3*64*LDW f16 : [0, 27648)
        float* bb = (float*)(smem + 27648);      // 3*64        : [27648, 28416)
        float* red = (float*)(smem + 28928);     // 512 f32     : [28928, 30976)
        for(int i = t; i < 3 * 4096; i += 256){
            int j = i >> 12, e = i & 4095, k = e >> 6, n = e & 63;
            const float* wp = (j == 0) ? w1 : ((j == 1) ? w2 : w3);
            wT[j * 64 * LDW + n * LDW + k] = (f16)wp[e];
        }
        if(t < 64){ bb[t] = b1[t]; bb[64 + t] = b2[t]; bb[128 + t] = b3[t]; }
        int c = t & 63, rg = t >> 6;
        int rb = bid * 64;
        float s = 0.f, s2 = 0.f;
        for(int r = rg; r < 64; r += 4){
            float v = x[(rb + r) * 64 + c];
            s += v; s2 += v * v;
        }
        red[t] = s; red[256 + t] = s2;
        if(bid == 0 && t < 128) sums[t] = 0.f;
    }
    grid.sync();
    // ---------------- P1: atomic reduce ----------------
    {
        float* red = (float*)(smem + 28928);
        if(t < 64){
            float a = red[t] + red[t + 64] + red[t + 128] + red[t + 192];
            float b = red[256 + t] + red[256 + t + 64] + red[256 + t + 128] + red[256 + t + 192];
            atomicAdd(&sums[t], a);
            atomicAdd(&sums[64 + t], b);
        }
    }
    grid.sync();
    // ---------------- P2: BN apply + QKV ----------------
    {
        f16*  wT  = (f16*)smem;
        float* bb = (float*)(smem + 27648);
        float* sc = (float*)(smem + 28416);      // 64
        float* sh = (float*)(smem + 28672);      // 64
        if(t < 64){
            float mean = sums[t] * (1.f / 16384.f);
            float var  = sums[64 + t] * (1.f / 16384.f) - mean * mean;
            float s = gamma[t] * rsqrtf(var + 1e-5f);
            sc[t] = s;
            sh[t] = beta[t] - mean * s;
        }
        __syncthreads();
        int w = t >> 6, lane = t & 63, quad = lane >> 4, l15 = lane & 15;
        int rowb = bid * 64 + w * 16;
        int arow = rowb + l15;
        half8 a[2];
        #pragma unroll
        for(int kc = 0; kc < 2; kc++){
            f32x4 x0 = *(const f32x4*)&x[arow * 64 + kc * 32 + quad * 8];
            f32x4 x1 = *(const f32x4*)&x[arow * 64 + kc * 32 + quad * 8 + 4];
            half8 h;
            #pragma unroll
            for(int j = 0; j < 8; j++){
                int c = kc * 32 + quad * 8 + j;
                float xv = (j < 4) ? x0[j & 3] : x1[j & 3];
                h[j] = (f16)(xv * sc[c] + sh[c]);
            }
            a[kc] = h;
        }
        const f32x4 vzero = {0.f, 0.f, 0.f, 0.f};
        f32x4 acc[3][4];
        #pragma unroll
        for(int m = 0; m < 3; m++){
            #pragma unroll
            for(int nt = 0; nt < 4; nt++){
                acc[m][nt] = vzero;
                #pragma unroll
                for(int kc = 0; kc < 2; kc++){
                    half8 bfr = *(half8*)&wT[m * 64 * LDW + (nt * 16 + l15) * LDW + kc * 32 + quad * 8];
                    acc[m][nt] = __builtin_amdgcn_mfma_f32_16x16x32_f16(a[kc], bfr, acc[m][nt], 0, 0, 0);
                }
            }
        }
        const float qs = 0.18033688011112043f;  // log2(e)/8
        #pragma unroll
        for(int nt = 0; nt < 4; nt++){
            #pragma unroll
            for(int r = 0; r < 4; r++){
                int row = rowb + quad * 4 + r;
                int col = nt * 16 + l15;
                Q[row * 64 + col]  = (f16)((acc[0][nt][r] + bb[col]) * qs);
                Kx[row * 64 + col] = (f16)(acc[1][nt][r] + bb[64 + col]);
                Vt[((row >> 12) * 64 + col) * 4096 + (row & 4095)] = (f16)(acc[2][nt][r] + bb[128 + col]);
            }
        }
    }
    grid.sync();
    // ---------------- P3: attention (two 256-row Q halves) ----------------
    {
        f16* KV = (f16*)smem;                    // [2][2*64*LDW] : 36864 B
        float* lred = (float*)(smem + 36864);    // [4][64]
        const int BUF = 2 * 64 * LDW;
        int kq = bid & 7, qg = bid >> 3;         // qg in [0,32)
        int w = t >> 6, lane = t & 63, l31 = lane & 31, hi = lane >> 5;

        for(int half = 0; half < 2; half++){
            int qg2 = qg * 2 + half;             // [0,64)
            int b = qg2 >> 4;
            int qrow0 = qg2 * 256 + w * 64;

            half8 aq[2][4];
            #pragma unroll
            for(int qt = 0; qt < 2; qt++)
                #pragma unroll
                for(int dc = 0; dc < 4; dc++)
                    aq[qt][dc] = *(const half8*)&Q[(qrow0 + qt * 32 + l31) * 64 + dc * 16 + hi * 8];

            const f16* gsrc[4];
            int loff[4], gstep[4];
            #pragma unroll
            for(int i = 0; i < 4; i++){
                int idx = t + i * 256;
                int rr = (idx >> 3) & 63, c8 = idx & 7, kt0 = kq * 8;
                if(idx < 512){
                    loff[i] = rr * LDW + c8 * 8;
                    gsrc[i] = &Kx[(b * 4096 + kt0 * 64 + rr) * 64 + c8 * 8];
                    gstep[i] = 64 * 64;
                } else {
                    loff[i] = 64 * LDW + rr * LDW + c8 * 8;
                    gsrc[i] = &Vt[(b * 64 + rr) * 4096 + kt0 * 64 + c8 * 8];
                    gstep[i] = 64;
                }
            }
            half8 pre[4];
            #pragma unroll
            for(int i = 0; i < 4; i++){ pre[i] = *(const half8*)gsrc[i]; gsrc[i] += gstep[i]; }
            #pragma unroll
            for(int i = 0; i < 4; i++) *(half8*)&KV[loff[i]] = pre[i];

            f32x16 o[2][2];
            #pragma unroll
            for(int qt = 0; qt < 2; qt++)
                #pragma unroll
                for(int dt = 0; dt < 2; dt++)
                    #pragma unroll
                    for(int r = 0; r < 16; r++) o[qt][dt][r] = 0.f;
            float lp[2] = {0.f, 0.f};

            __syncthreads();
            int cur = 0;
            for(int j = 0; j < 8; j++){
                if(j < 7){
                    #pragma unroll
                    for(int i = 0; i < 4; i++){ pre[i] = *(const half8*)gsrc[i]; gsrc[i] += gstep[i]; }
                }
                const f16* Kb = KV + cur * BUF;
                const f16* Vb = Kb + 64 * LDW;
                #pragma unroll
                for(int kt = 0; kt < 2; kt++){
                    half8 ak[4];
                    #pragma unroll
                    for(int dc = 0; dc < 4; dc++)
                        ak[dc] = *(const half8*)&Kb[(kt * 32 + l31) * LDW + dc * 16 + hi * 8];
                    half8 vb[2][2];
                    #pragma unroll
                    for(int kc = 0; kc < 2; kc++)
                        #pragma unroll
                        for(int dt = 0; dt < 2; dt++)
                            vb[kc][dt] = *(const half8*)&Vb[(dt * 32 + l31) * LDW + kt * 32 + kc * 16 + hi * 8];
                    #pragma unroll
                    for(int qt = 0; qt < 2; qt++){
                        f32x16 s;
                        #pragma unroll
                        for(int r = 0; r < 16; r++) s[r] = 0.f;
                        #pragma unroll
                        for(int dc = 0; dc < 4; dc++)
                            s = __builtin_amdgcn_mfma_f32_32x32x16_f16(ak[dc], aq[qt][dc], s, 0, 0, 0);
                        float pf[16], ls = 0.f;
                        #pragma unroll
                        for(int r = 0; r < 16; r++){
                            float p = __builtin_amdgcn_exp2f(fminf(s[r], 15.f));
                            pf[r] = p; ls += p;
                        }
                        lp[qt] += ls;
                        unsigned wv[4][2];
                        #pragma unroll
                        for(int g = 0; g < 4; g++){
                            wv[g][0] = __builtin_bit_cast(unsigned, __builtin_amdgcn_cvt_pkrtz(pf[4*g+0], pf[4*g+1]));
                            wv[g][1] = __builtin_bit_cast(unsigned, __builtin_amdgcn_cvt_pkrtz(pf[4*g+2], pf[4*g+3]));
                        }
                        #pragma unroll
                        for(int kc = 0; kc < 2; kc++){
                            unsigned x0 = wv[2*kc][0], y0 = wv[2*kc+1][0];
                            unsigned x1 = wv[2*kc][1], y1 = wv[2*kc+1][1];
                            asm("v_permlane32_swap_b32 %0, %1" : "+v"(x0), "+v"(y0));
                            asm("v_permlane32_swap_b32 %0, %1" : "+v"(x1), "+v"(y1));
                            u32x4 pw = {x0, x1, y0, y1};
                            half8 pa = __builtin_bit_cast(half8, pw);
                            #pragma unroll
                            for(int dt = 0; dt < 2; dt++)
                                o[qt][dt] = __builtin_amdgcn_mfma_f32_32x32x16_f16(pa, vb[kc][dt], o[qt][dt], 0, 0, 0);
                        }
                    }
                }
                if(j < 7){
                    f16* wb = KV + (cur ^ 1) * BUF;
                    #pragma unroll
                    for(int i = 0; i < 4; i++) *(half8*)(wb + loff[i]) = pre[i];
                }
                cur ^= 1;
                __syncthreads();
            }
            #pragma unroll
            for(int qt = 0; qt < 2; qt++){
                float v = lp[qt] + __shfl_xor(lp[qt], 32);
                if(hi == 0){
                    int row = qrow0 + qt * 32 + l31;
                    lw[kq * 16384 + row] = v;
                    lred[w * 64 + qt * 32 + l31] = __builtin_amdgcn_rcpf(v);
                }
            }
            #pragma unroll
            for(int qt = 0; qt < 2; qt++)
                #pragma unroll
                for(int r = 0; r < 16; r++){
                    int qrl = qt * 32 + (r & 3) + 8 * (r >> 2) + 4 * hi;
                    float inv = lred[w * 64 + qrl];
                    int row = qrow0 + qrl;
                    #pragma unroll
                    for(int dt = 0; dt < 2; dt++)
                        Oph[kq * 1048576 + row * 64 + dt * 32 + l31] = (f16)(o[qt][dt][r] * inv);
                }
        }
    }
    grid.sync();
    // ---------------- P4: merge + W4 + residual ----------------
    {
        f16* Om  = (f16*)smem;                   // 64*LDW f16 : [0, 9216)
        f16* wT4 = (f16*)(smem + 9216);          // 64*LDW f16 : [9216, 18432)
        float* b4f = (float*)(smem + 18432);     // 64
        int rb = bid * 64;
        for(int i = t; i < 4096; i += 256){
            int k = i >> 6, n = i & 63;
            wT4[n * LDW + k] = (f16)w4[i];
        }
        if(t < 64) b4f[t] = b4[t];
        for(int i = t; i < 512; i += 256){
            int row = i >> 3, c8 = i & 7;
            int gr = rb + row;
            float num[8] = {0.f,0.f,0.f,0.f,0.f,0.f,0.f,0.f};
            float den = 0.f;
            #pragma unroll
            for(int s = 0; s < 8; s++){
                float li = lw[s * 16384 + gr];
                half8 ov = *(const half8*)&Oph[s * 1048576 + gr * 64 + c8 * 8];
                #pragma unroll
                for(int j = 0; j < 8; j++) num[j] += li * (float)ov[j];
                den += li;
            }
            float invd = 1.f / den;
            #pragma unroll
            for(int j = 0; j < 8; j++) Om[row * LDW + c8 * 8 + j] = (f16)(num[j] * invd);
        }
        __syncthreads();
        int w = t >> 6, lane = t & 63, quad = lane >> 4, l15 = lane & 15;
        half8 a[2];
        #pragma unroll
        for(int kc = 0; kc < 2; kc++)
            a[kc] = *(half8*)&Om[(w * 16 + l15) * LDW + kc * 32 + quad * 8];
        #pragma unroll
        for(int nt = 0; nt < 4; nt++){
            f32x4 y = {0.f, 0.f, 0.f, 0.f};
            #pragma unroll
            for(int kc = 0; kc < 2; kc++){
                half8 bfr = *(half8*)&wT4[(nt * 16 + l15) * LDW + kc * 32 + quad * 8];
                y = __builtin_amdgcn_mfma_f32_16x16x32_f16(a[kc], bfr, y, 0, 0, 0);
            }
            #pragma unroll
            for(int r = 0; r < 4; r++){
                int row = rb + w * 16 + quad * 4 + r;
                int col = nt * 16 + l15;
                out[row * 64 + col] = y[r] + b4f[col] + x[row * 64 + col];
            }
        }
    }
}

// ================= fallback pipeline (round-1, verified) =================
__global__ __launch_bounds__(256) void k_bnstats(const float* __restrict__ x, float* __restrict__ sums){
    __shared__ float red[512];
    int t = threadIdx.x;
    int c = t & 63, rg = t >> 6;
    int rb = blockIdx.x * 64;
    float s = 0.f, s2 = 0.f;
    for(int r = rg; r < 64; r += 4){
        float v = x[(rb + r) * 64 + c];
        s += v; s2 += v * v;
    }
    red[t] = s; red[256 + t] = s2;
    __syncthreads();
    if(t < 64){
        float a = red[t] + red[t + 64] + red[t + 128] + red[t + 192];
        float b = red[256 + t] + red[256 + t + 64] + red[256 + t + 128] + red[256 + t + 192];
        atomicAdd(&sums[c], a);
        atomicAdd(&sums[64 + c], b);
    }
}

__global__ __launch_bounds__(256) void k_qkv(
    const float* __restrict__ x,
    const float* __restrict__ w1, const float* __restrict__ w2, const float* __restrict__ w3,
    const float* __restrict__ b1, const float* __restrict__ b2, const float* __restrict__ b3,
    const float* __restrict__ gamma, const float* __restrict__ beta,
    const float* __restrict__ sums,
    f16* __restrict__ Q, f16* __restrict__ Kx, f16* __restrict__ Vt){
    __shared__ f16 wT[3 * 64 * LDW];
    __shared__ float sc[64], sh[64], bb[3][64];
    int t = threadIdx.x;
    for(int i = t; i < 3 * 4096; i += 256){
        int j = i >> 12, e = i & 4095, k = e >> 6, n = e & 63;
        const float* wp = (j == 0) ? w1 : ((j == 1) ? w2 : w3);
        wT[j * 64 * LDW + n * LDW + k] = (f16)wp[e];
    }
    if(t < 64){
        float mean = sums[t] * (1.f / 16384.f);
        float var  = sums[64 + t] * (1.f / 16384.f) - mean * mean;
        float s = gamma[t] * rsqrtf(var + 1e-5f);
        sc[t] = s;
        sh[t] = beta[t] - mean * s;
        bb[0][t] = b1[t]; bb[1][t] = b2[t]; bb[2][t] = b3[t];
    }
    __syncthreads();
    int w = t >> 6, lane = t & 63, quad = lane >> 4, l15 = lane & 15;
    int rowb = blockIdx.x * 64 + w * 16;
    int arow = rowb + l15;
    half8 a[2];
    #pragma unroll
    for(int kc = 0; kc < 2; kc++){
        f32x4 x0 = *(const f32x4*)&x[arow * 64 + kc * 32 + quad * 8];
        f32x4 x1 = *(const f32x4*)&x[arow * 64 + kc * 32 + quad * 8 + 4];
        half8 h;
        #pragma unroll
        for(int j = 0; j < 8; j++){
            int c = kc * 32 + quad * 8 + j;
            float xv = (j < 4) ? x0[j & 3] : x1[j & 3];
            h[j] = (f16)(xv * sc[c] + sh[c]);
        }
        a[kc] = h;
    }
    const f32x4 vzero = {0.f, 0.f, 0.f, 0.f};
    f32x4 acc[3][4];
    #pragma unroll
    for(int m = 0; m < 3; m++){
        #pragma unroll
        for(int nt = 0; nt < 4; nt++){
            acc[m][nt] = vzero;
            #pragma unroll
            for(int kc = 0; kc < 2; kc++){
                half8 bfr = *(half8*)&wT[m * 64 * LDW + (nt * 16 + l15) * LDW + kc * 32 + quad * 8];
                acc[m][nt] = __builtin_amdgcn_mfma_f32_16x16x32_f16(a[kc], bfr, acc[m][nt], 0, 0, 0);
            }
        }
    }
    const float qs = 0.18033688011112043f;
    #pragma unroll
    for(int nt = 0; nt < 4; nt++){
        #pragma unroll
        for(int r = 0; r < 4; r++){
            int row = rowb + quad * 4 + r;
            int col = nt * 16 + l15;
            Q[row * 64 + col]  = (f16)((acc[0][nt][r] + bb[0][col]) * qs);
            Kx[row * 64 + col] = (f16)(acc[1][nt][r] + bb[1][col]);
            Vt[((row >> 12) * 64 + col) * 4096 + (row & 4095)] = (f16)(acc[2][nt][r] + bb[2][col]);
        }
    }
}

__global__ __launch_bounds__(256, 2) void k_attn(
    const f16* __restrict__ Q, const f16* __restrict__ Kx, const f16* __restrict__ Vt,
    f16* __restrict__ Oph, float* __restrict__ lw){
    __shared__ f16 KV[2][2 * 64 * LDW];
    __shared__ float lred[4][64];
    int t = threadIdx.x;
    int kq = blockIdx.x & 7, qg = blockIdx.x >> 3;
    int b = qg >> 4;
    int w = t >> 6, lane = t & 63, l31 = lane & 31, hi = lane >> 5;
    int qrow0 = qg * 256 + w * 64;
    const int BUF = 2 * 64 * LDW;

    half8 aq[2][4];
    #pragma unroll
    for(int qt = 0; qt < 2; qt++)
        #pragma unroll
        for(int dc = 0; dc < 4; dc++)
            aq[qt][dc] = *(const half8*)&Q[(qrow0 + qt * 32 + l31) * 64 + dc * 16 + hi * 8];

    const f16* gsrc[4];
    int loff[4], gstep[4];
    #pragma unroll
    for(int i = 0; i < 4; i++){
        int idx = t + i * 256;
        int rr = (idx >> 3) & 63, c8 = idx & 7, kt0 = kq * 8;
        if(idx < 512){
            loff[i] = rr * LDW + c8 * 8;
            gsrc[i] = &Kx[(b * 4096 + kt0 * 64 + rr) * 64 + c8 * 8];
            gstep[i] = 64 * 64;
        } else {
            loff[i] = 64 * LDW + rr * LDW + c8 * 8;
            gsrc[i] = &Vt[(b * 64 + rr) * 4096 + kt0 * 64 + c8 * 8];
            gstep[i] = 64;
        }
    }
    half8 pre[4];
    #pragma unroll
    for(int i = 0; i < 4; i++){ pre[i] = *(const half8*)gsrc[i]; gsrc[i] += gstep[i]; }
    #pragma unroll
    for(int i = 0; i < 4; i++) *(half8*)&KV[0][loff[i]] = pre[i];

    f32x16 o[2][2];
    #pragma unroll
    for(int qt = 0; qt < 2; qt++)
        #pragma unroll
        for(int dt = 0; dt < 2; dt++)
            #pragma unroll
            for(int r = 0; r < 16; r++) o[qt][dt][r] = 0.f;
    float lp[2] = {0.f, 0.f};

    __syncthreads();
    int cur = 0;
    for(int j = 0; j < 8; j++){
        if(j < 7){
            #pragma unroll
            for(int i = 0; i < 4; i++){ pre[i] = *(const half8*)gsrc[i]; gsrc[i] += gstep[i]; }
        }
        const f16* Kb = &KV[0][0] + cur * BUF;
        const f16* Vb = Kb + 64 * LDW;
        #pragma unroll
        for(int kt = 0; kt < 2; kt++){
            half8 ak[4];
            #pragma unroll
            for(int dc = 0; dc < 4; dc++)
                ak[dc] = *(const half8*)&Kb[(kt * 32 + l31) * LDW + dc * 16 + hi * 8];
            half8 vb[2][2];
            #pragma unroll
            for(int kc = 0; kc < 2; kc++)
                #pragma unroll
                for(int dt = 0; dt < 2; dt++)
                    vb[kc][dt] = *(const half8*)&Vb[(dt * 32 + l31) * LDW + kt * 32 + kc * 16 + hi * 8];
            #pragma unroll
            for(int qt = 0; qt < 2; qt++){
                f32x16 s;
                #pragma unroll
                for(int r = 0; r < 16; r++) s[r] = 0.f;
                #pragma unroll
                for(int dc = 0; dc < 4; dc++)
                    s = __builtin_amdgcn_mfma_f32_32x32x16_f16(ak[dc], aq[qt][dc], s, 0, 0, 0);
                float pf[16], ls = 0.f;
                #pragma unroll
                for(int r = 0; r < 16; r++){
                    float p = __builtin_amdgcn_exp2f(fminf(s[r], 15.f));
                    pf[r] = p; ls += p;
                }
                lp[qt] += ls;
                unsigned wv[4][2];
                #pragma unroll
                for(int g = 0; g < 4; g++){
                    wv[g][0] = __builtin_bit_cast(unsigned, __builtin_amdgcn_cvt_pkrtz(pf[4*g+0], pf[4*g+1]));
                    wv[g][1] = __builtin_bit_cast(unsigned, __builtin_amdgcn_cvt_pkrtz(pf[4*g+2], pf[4*g+3]));
                }
                #pragma unroll
                for(int kc = 0; kc < 2; kc++){
                    unsigned x0 = wv[2*kc][0], y0 = wv[2*kc+1][0];
                    unsigned x1 = wv[2*kc][1], y1 = wv[2*kc+1][1];
                    asm("v_permlane32_swap_b32 %0, %1" : "+v"(x0), "+v"(y0));
                    asm("v_permlane32_swap_b32 %0, %1" : "+v"(x1), "+v"(y1));
                    u32x4 pw = {x0, x1, y0, y1};
                    half8 pa = __builtin_bit_cast(half8, pw);
                    #pragma unroll
                    for(int dt = 0; dt < 2; dt++)
                        o[qt][dt] = __builtin_amdgcn_mfma_f32_32x32x16_f16(pa, vb[kc][dt], o[qt][dt], 0, 0, 0);
                }
            }
        }
        if(j < 7){
            f16* wb = &KV[0][0] + (cur ^ 1) * BUF;
            #pragma unroll
            for(int i = 0; i < 4; i++) *(half8*)(wb + loff[i]) = pre[i];
        }
        cur ^= 1;
        __syncthreads();
    }
    #pragma unroll
    for(int qt = 0; qt < 2; qt++){
        float v = lp[qt] + __shfl_xor(lp[qt], 32);
        if(hi == 0){
            int row = qrow0 + qt * 32 + l31;
            lw[kq * 16384 + row] = v;
            lred[w][qt * 32 + l31] = __builtin_amdgcn_rcpf(v);
        }
    }
    #pragma unroll
    for(int qt = 0; qt < 2; qt++)
        #pragma unroll
        for(int r = 0; r < 16; r++){
            int qrl = qt * 32 + (r & 3) + 8 * (r >> 2) + 4 * hi;
            float inv = lred[w][qrl];
            int row = qrow0 + qrl;
            #pragma unroll
            for(int dt = 0; dt < 2; dt++)
                Oph[kq * 1048576 + row * 64 + dt * 32 + l31] = (f16)(o[qt][dt][r] * inv);
        }
}

__global__ __launch_bounds__(256) void k_merge(
    const f16* __restrict__ Oph, const float* __restrict__ lw,
    const float* __restrict__ w4, const float* __restrict__ b4,
    const float* __restrict__ x, float* __restrict__ out){
    __shared__ f16 Om[64 * LDW];
    __shared__ f16 wT[64 * LDW];
    __shared__ float b4f[64];
    int t = threadIdx.x;
    int rb = blockIdx.x * 64;
    for(int i = t; i < 4096; i += 256){
        int k = i >> 6, n = i & 63;
        wT[n * LDW + k] = (f16)w4[i];
    }
    if(t < 64) b4f[t] = b4[t];
    for(int i = t; i < 512; i += 256){
        int row = i >> 3, c8 = i & 7;
        int gr = rb + row;
        float num[8] = {0.f,0.f,0.f,0.f,0.f,0.f,0.f,0.f};
        float den = 0.f;
        #pragma unroll
        for(int s = 0; s < 8; s++){
            float li = lw[s * 16384 + gr];
            half8 ov = *(const half8*)&Oph[s * 1048576 + gr * 64 + c8 * 8];
            #pragma unroll
            for(int j = 0; j < 8; j++) num[j] += li * (float)ov[j];
            den += li;
        }
        float invd = 1.f / den;
        #pragma unroll
        for(int j = 0; j < 8; j++) Om[row * LDW + c8 * 8 + j] = (f16)(num[j] * invd);
    }
    __syncthreads();
    int w = t >> 6, lane = t & 63, quad = lane >> 4, l15 = lane & 15;
    half8 a[2];
    #pragma unroll
    for(int kc = 0; kc < 2; kc++)
        a[kc] = *(half8*)&Om[(w * 16 + l15) * LDW + kc * 32 + quad * 8];
    #pragma unroll
    for(int nt = 0; nt < 4; nt++){
        f32x4 y = {0.f, 0.f, 0.f, 0.f};
        #pragma unroll
        for(int kc = 0; kc < 2; kc++){
            half8 bfr = *(half8*)&wT[(nt * 16 + l15) * LDW + kc * 32 + quad * 8];
            y = __builtin_amdgcn_mfma_f32_16x16x32_f16(a[kc], bfr, y, 0, 0, 0);
        }
        #pragma unroll
        for(int r = 0; r < 4; r++){
            int row = rb + w * 16 + quad * 4 + r;
            int col = nt * 16 + l15;
            out[row * 64 + col] = y[r] + b4f[col] + x[row * 64 + col];
        }
    }
}

extern "C" void kernel_launch(void* const* d_in, const int* in_sizes, int n_in,
                              void* d_out, int out_size, void* d_ws, size_t ws_size,
                              hipStream_t stream){
    (void)in_sizes; (void)n_in; (void)out_size; (void)ws_size;
    const float* x  = (const float*)d_in[0];
    const float* w1 = (const float*)d_in[1];
    const float* w2 = (const float*)d_in[2];
    const float* w3 = (const float*)d_in[3];
    const float* w4 = (const float*)d_in[4];
    const float* b1 = (const float*)d_in[5];
    const float* b2 = (const float*)d_in[6];
    const float* b3 = (const float*)d_in[7];
    const float* b4 = (const float*)d_in[8];
    const float* gm = (const float*)d_in[9];
    const float* bt = (const float*)d_in[10];
    char* ws = (char*)d_ws;
    f16* Q   = (f16*)(ws);
    f16* Kx  = (f16*)(ws + (size_t)(2u << 20));
    f16* Vt  = (f16*)(ws + (size_t)(4u << 20));
    float* sums = (float*)(ws + (size_t)(6u << 20));
    f16* Oph = (f16*)(ws + (size_t)(6u << 20) + 1024);                       // 8 x 2MB (f16, normalized)
    float* lwp = (float*)(ws + (size_t)(22u << 20) + 1024);                  // 8 x 64KB
    float* outp = (float*)d_out;

    void* args[18];
    args[0]  = (void*)&x;   args[1]  = (void*)&w1;  args[2]  = (void*)&w2;
    args[3]  = (void*)&w3;  args[4]  = (void*)&w4;  args[5]  = (void*)&b1;
    args[6]  = (void*)&b2;  args[7]  = (void*)&b3;  args[8]  = (void*)&b4;
    args[9]  = (void*)&gm;  args[10] = (void*)&bt;  args[11] = (void*)&sums;
    args[12] = (void*)&Q;   args[13] = (void*)&Kx;  args[14] = (void*)&Vt;
    args[15] = (void*)&Oph; args[16] = (void*)&lwp; args[17] = (void*)&outp;

    hipError_t rc = hipLaunchCooperativeKernel((const void*)k_fused, dim3(256), dim3(256), args, 0, stream);
    if(rc != hipSuccess){
        // fallback: verified 5-dispatch pipeline
        hipMemsetAsync(sums, 0, 512, stream);
        hipLaunchKernelGGL(k_bnstats, dim3(256), dim3(256), 0, stream, x, sums);
        hipLaunchKernelGGL(k_qkv,     dim3(256), dim3(256), 0, stream, x, w1, w2, w3, b1, b2, b3, gm, bt, sums, Q, Kx, Vt);
        hipLaunchKernelGGL(k_attn,    dim3(512), dim3(256), 0, stream, Q, Kx, Vt, Oph, lwp);
        hipLaunchKernelGGL(k_merge,   dim3(256), dim3(256), 0, stream, Oph, lwp, w4, b4, x, (float*)d_out);
    }
}

// Round 4
// 130.852 us; speedup vs baseline: 1.9183x; 1.9183x over previous
//
#include <hip/hip_runtime.h>

typedef _Float16 f16;
typedef _Float16 half8 __attribute__((ext_vector_type(8)));
typedef float f32x4 __attribute__((ext_vector_type(4)));
typedef float f32x16 __attribute__((ext_vector_type(16)));
typedef unsigned u32x4 __attribute__((ext_vector_type(4)));

#define LDW 72  // padded LDS leading dim (f16): 144B row stride

// ---------------- K1: BatchNorm statistics -> per-block partials (no atomics, no memset) ----------------
__global__ __launch_bounds__(256) void k_bnstats(const float* __restrict__ x, float* __restrict__ part){
    __shared__ float red[512];
    int t = threadIdx.x;
    int c = t & 63, rg = t >> 6;
    int rb = blockIdx.x * 64;
    float s = 0.f, s2 = 0.f;
    for(int r = rg; r < 64; r += 4){
        float v = x[(rb + r) * 64 + c];
        s += v; s2 += v * v;
    }
    red[t] = s; red[256 + t] = s2;
    __syncthreads();
    if(t < 128){
        int c2 = t & 63, h = t >> 6;    // h=0: sum, h=1: sumsq
        float a = red[h * 256 + c2] + red[h * 256 + c2 + 64] + red[h * 256 + c2 + 128] + red[h * 256 + c2 + 192];
        part[blockIdx.x * 128 + t] = a; // [bid][0..63 sum | 64..127 sumsq]
    }
}

// ---------------- K2: partial-reduce + BN apply + QKV projections ----------------
__global__ __launch_bounds__(256) void k_qkv(
    const float* __restrict__ x,
    const float* __restrict__ w1, const float* __restrict__ w2, const float* __restrict__ w3,
    const float* __restrict__ b1, const float* __restrict__ b2, const float* __restrict__ b3,
    const float* __restrict__ gamma, const float* __restrict__ beta,
    const float* __restrict__ part,
    f16* __restrict__ Q, f16* __restrict__ Kx, f16* __restrict__ Vt){
    __shared__ f16 wT[3 * 64 * LDW];      // weights transposed: wT[j][n][k] = wj[k][n]
    __shared__ float sc[64], sh[64], bb[3][64];
    __shared__ float psum[128];
    int t = threadIdx.x;
    for(int i = t; i < 3 * 4096; i += 256){
        int j = i >> 12, e = i & 4095, k = e >> 6, n = e & 63;
        const float* wp = (j == 0) ? w1 : ((j == 1) ? w2 : w3);
        wT[j * 64 * LDW + n * LDW + k] = (f16)wp[e];
    }
    if(t < 128){
        float a0 = 0.f, a1 = 0.f, a2 = 0.f, a3 = 0.f;
        for(int b = 0; b < 256; b += 4){
            a0 += part[b * 128 + t];       a1 += part[(b + 1) * 128 + t];
            a2 += part[(b + 2) * 128 + t]; a3 += part[(b + 3) * 128 + t];
        }
        psum[t] = (a0 + a1) + (a2 + a3);
    }
    __syncthreads();
    if(t < 64){
        float mean = psum[t] * (1.f / 16384.f);
        float var  = psum[64 + t] * (1.f / 16384.f) - mean * mean;
        float s = gamma[t] * rsqrtf(var + 1e-5f);
        sc[t] = s;
        sh[t] = beta[t] - mean * s;
        bb[0][t] = b1[t]; bb[1][t] = b2[t]; bb[2][t] = b3[t];
    }
    __syncthreads();
    int w = t >> 6, lane = t & 63, quad = lane >> 4, l15 = lane & 15;
    int rowb = blockIdx.x * 64 + w * 16;
    int arow = rowb + l15;
    half8 a[2];
    #pragma unroll
    for(int kc = 0; kc < 2; kc++){
        f32x4 x0 = *(const f32x4*)&x[arow * 64 + kc * 32 + quad * 8];
        f32x4 x1 = *(const f32x4*)&x[arow * 64 + kc * 32 + quad * 8 + 4];
        half8 h;
        #pragma unroll
        for(int j = 0; j < 8; j++){
            int c = kc * 32 + quad * 8 + j;
            float xv = (j < 4) ? x0[j & 3] : x1[j & 3];
            h[j] = (f16)(xv * sc[c] + sh[c]);
        }
        a[kc] = h;
    }
    const f32x4 vzero = {0.f, 0.f, 0.f, 0.f};
    f32x4 acc[3][4];
    #pragma unroll
    for(int m = 0; m < 3; m++){
        #pragma unroll
        for(int nt = 0; nt < 4; nt++){
            acc[m][nt] = vzero;
            #pragma unroll
            for(int kc = 0; kc < 2; kc++){
                half8 bfr = *(half8*)&wT[m * 64 * LDW + (nt * 16 + l15) * LDW + kc * 32 + quad * 8];
                acc[m][nt] = __builtin_amdgcn_mfma_f32_16x16x32_f16(a[kc], bfr, acc[m][nt], 0, 0, 0);
            }
        }
    }
    const float qs = 0.18033688011112043f;  // log2(e)/8 : folds softmax scale + exp2 base change into Q
    #pragma unroll
    for(int nt = 0; nt < 4; nt++){
        #pragma unroll
        for(int r = 0; r < 4; r++){
            int row = rowb + quad * 4 + r;
            int col = nt * 16 + l15;
            Q[row * 64 + col]  = (f16)((acc[0][nt][r] + bb[0][col]) * qs);
            Kx[row * 64 + col] = (f16)(acc[1][nt][r] + bb[1][col]);
            Vt[((row >> 12) * 64 + col) * 4096 + (row & 4095)] = (f16)(acc[2][nt][r] + bb[2][col]);
        }
    }
}

// ---------------- K3: streaming attention, swapped-QK^T 32x32x16, in-register softmax ----------------
// grid 1024: kq = bid&7 (K-eighth), qg = bid>>3 (128 x 128-row Q groups). 4 blocks/CU, 16 waves/CU.
// 32 Q-rows/wave (halved register state vs 64-row version -> fits launch_bounds(256,4)).
// S^T = mfma(A=K, B=Q): lane holds one qrow (lane&31), 16 kcols in regs -> exp + cvt_pkrtz +
// v_permlane32_swap assemble the PV A-fragment fully in registers (no P LDS round-trip).
// Partials stored NORMALIZED (o/l) as f16 + l as fp32; merged as weighted average.
__global__ __launch_bounds__(256, 4) void k_attn(
    const f16* __restrict__ Q, const f16* __restrict__ Kx, const f16* __restrict__ Vt,
    f16* __restrict__ Oph, float* __restrict__ lw){
    __shared__ f16 KV[2][2 * 64 * LDW];
    __shared__ float lred[4][32];
    int t = threadIdx.x;
    int kq = blockIdx.x & 7, qg = blockIdx.x >> 3;   // qg in [0,128)
    int b = qg >> 5;                                 // batch image (32 groups of 128 rows each)
    int w = t >> 6, lane = t & 63, l31 = lane & 31, hi = lane >> 5;
    int qrow0 = qg * 128 + w * 32;
    const int BUF = 2 * 64 * LDW;

    // Q fragments (B-operand): lane holds qrow = qrow0+l31, d-elems dc*16 + hi*8 .. +7
    half8 aq[4];
    #pragma unroll
    for(int dc = 0; dc < 4; dc++)
        aq[dc] = *(const half8*)&Q[(qrow0 + l31) * 64 + dc * 16 + hi * 8];

    // staging: 1024 x 16B chunks per 64-col tile (512 K + 512 V^T); 4 chunks/thread
    const f16* gsrc[4];
    int loff[4], gstep[4];
    #pragma unroll
    for(int i = 0; i < 4; i++){
        int idx = t + i * 256;
        int rr = (idx >> 3) & 63, c8 = idx & 7, kt0 = kq * 8;
        if(idx < 512){
            loff[i] = rr * LDW + c8 * 8;
            gsrc[i] = &Kx[(b * 4096 + kt0 * 64 + rr) * 64 + c8 * 8];
            gstep[i] = 64 * 64;
        } else {
            loff[i] = 64 * LDW + rr * LDW + c8 * 8;
            gsrc[i] = &Vt[(b * 64 + rr) * 4096 + kt0 * 64 + c8 * 8];
            gstep[i] = 64;
        }
    }
    half8 pre[4];
    #pragma unroll
    for(int i = 0; i < 4; i++){ pre[i] = *(const half8*)gsrc[i]; gsrc[i] += gstep[i]; }
    #pragma unroll
    for(int i = 0; i < 4; i++) *(half8*)&KV[0][loff[i]] = pre[i];

    f32x16 o[2];
    #pragma unroll
    for(int dt = 0; dt < 2; dt++)
        #pragma unroll
        for(int r = 0; r < 16; r++) o[dt][r] = 0.f;
    float lp = 0.f;

    __syncthreads();
    int cur = 0;
    for(int j = 0; j < 8; j++){
        if(j < 7){  // issue next-tile global loads early; consumed after compute (T14)
            #pragma unroll
            for(int i = 0; i < 4; i++){ pre[i] = *(const half8*)gsrc[i]; gsrc[i] += gstep[i]; }
        }
        const f16* Kb = &KV[0][0] + cur * BUF;
        const f16* Vb = Kb + 64 * LDW;
        #pragma unroll
        for(int kt = 0; kt < 2; kt++){
            // K fragments (A-operand): lane holds kcol = kt*32+l31, d-elems dc*16 + hi*8
            half8 ak[4];
            #pragma unroll
            for(int dc = 0; dc < 4; dc++)
                ak[dc] = *(const half8*)&Kb[(kt * 32 + l31) * LDW + dc * 16 + hi * 8];
            // V fragments (B-operand): lane holds d = dt*32+l31, kcols kt*32 + kc*16 + hi*8
            half8 vb[2][2];
            #pragma unroll
            for(int kc = 0; kc < 2; kc++)
                #pragma unroll
                for(int dt = 0; dt < 2; dt++)
                    vb[kc][dt] = *(const half8*)&Vb[(dt * 32 + l31) * LDW + kt * 32 + kc * 16 + hi * 8];
            f32x16 s;
            #pragma unroll
            for(int r = 0; r < 16; r++) s[r] = 0.f;
            #pragma unroll
            for(int dc = 0; dc < 4; dc++)
                s = __builtin_amdgcn_mfma_f32_32x32x16_f16(ak[dc], aq[dc], s, 0, 0, 0);
            // S^T layout: lane's 16 values all belong to qrow = qrow0+l31; kcol_local = (r&3)+8*(r>>2)+4*hi
            float pf[16], ls = 0.f;
            #pragma unroll
            for(int r = 0; r < 16; r++){
                float p = __builtin_amdgcn_exp2f(fminf(s[r], 15.f));
                pf[r] = p; ls += p;
            }
            lp += ls;
            unsigned wv[4][2];
            #pragma unroll
            for(int g = 0; g < 4; g++){
                wv[g][0] = __builtin_bit_cast(unsigned, __builtin_amdgcn_cvt_pkrtz(pf[4*g+0], pf[4*g+1]));
                wv[g][1] = __builtin_bit_cast(unsigned, __builtin_amdgcn_cvt_pkrtz(pf[4*g+2], pf[4*g+3]));
            }
            // A-frag chunk kc (16 kcols): lane hi needs kcols kc*16+hi*8..+7
            #pragma unroll
            for(int kc = 0; kc < 2; kc++){
                unsigned x0 = wv[2*kc][0], y0 = wv[2*kc+1][0];
                unsigned x1 = wv[2*kc][1], y1 = wv[2*kc+1][1];
                asm("v_permlane32_swap_b32 %0, %1" : "+v"(x0), "+v"(y0));
                asm("v_permlane32_swap_b32 %0, %1" : "+v"(x1), "+v"(y1));
                u32x4 pw = {x0, x1, y0, y1};
                half8 pa = __builtin_bit_cast(half8, pw);
                #pragma unroll
                for(int dt = 0; dt < 2; dt++)
                    o[dt] = __builtin_amdgcn_mfma_f32_32x32x16_f16(pa, vb[kc][dt], o[dt], 0, 0, 0);
            }
        }
        if(j < 7){
            f16* wb = &KV[0][0] + (cur ^ 1) * BUF;
            #pragma unroll
            for(int i = 0; i < 4; i++) *(half8*)(wb + loff[i]) = pre[i];
        }
        cur ^= 1;
        __syncthreads();
    }
    // row sums: lanes l and l+32 hold the same qrow
    {
        float v = lp + __shfl_xor(lp, 32);
        if(hi == 0){
            int row = qrow0 + l31;
            lw[kq * 16384 + row] = v;
            lred[w][l31] = __builtin_amdgcn_rcpf(v);
        }
    }
    // O layout: lane holds d = dt*32+l31; qrow = (r&3)+8*(r>>2)+4*hi
    #pragma unroll
    for(int r = 0; r < 16; r++){
        int qrl = (r & 3) + 8 * (r >> 2) + 4 * hi;
        float inv = lred[w][qrl];
        int row = qrow0 + qrl;
        #pragma unroll
        for(int dt = 0; dt < 2; dt++)
            Oph[kq * 1048576 + row * 64 + dt * 32 + l31] = (f16)(o[dt][r] * inv);
    }
}

// ---------------- K4: weighted merge of normalized partials, W4 projection + bias + residual ----------------
__global__ __launch_bounds__(256) void k_merge(
    const f16* __restrict__ Oph, const float* __restrict__ lw,
    const float* __restrict__ w4, const float* __restrict__ b4,
    const float* __restrict__ x, float* __restrict__ out){
    __shared__ f16 Om[64 * LDW];
    __shared__ f16 wT[64 * LDW];
    __shared__ float b4f[64];
    int t = threadIdx.x;
    int rb = blockIdx.x * 64;
    for(int i = t; i < 4096; i += 256){
        int k = i >> 6, n = i & 63;
        wT[n * LDW + k] = (f16)w4[i];
    }
    if(t < 64) b4f[t] = b4[t];
    for(int i = t; i < 512; i += 256){
        int row = i >> 3, c8 = i & 7;
        int gr = rb + row;
        float num[8] = {0.f,0.f,0.f,0.f,0.f,0.f,0.f,0.f};
        float den = 0.f;
        #pragma unroll
        for(int s = 0; s < 8; s++){
            float li = lw[s * 16384 + gr];
            half8 ov = *(const half8*)&Oph[s * 1048576 + gr * 64 + c8 * 8];
            #pragma unroll
            for(int j = 0; j < 8; j++) num[j] += li * (float)ov[j];
            den += li;
        }
        float invd = 1.f / den;
        #pragma unroll
        for(int j = 0; j < 8; j++) Om[row * LDW + c8 * 8 + j] = (f16)(num[j] * invd);
    }
    __syncthreads();
    int w = t >> 6, lane = t & 63, quad = lane >> 4, l15 = lane & 15;
    half8 a[2];
    #pragma unroll
    for(int kc = 0; kc < 2; kc++)
        a[kc] = *(half8*)&Om[(w * 16 + l15) * LDW + kc * 32 + quad * 8];
    #pragma unroll
    for(int nt = 0; nt < 4; nt++){
        f32x4 y = {0.f, 0.f, 0.f, 0.f};
        #pragma unroll
        for(int kc = 0; kc < 2; kc++){
            half8 bfr = *(half8*)&wT[(nt * 16 + l15) * LDW + kc * 32 + quad * 8];
            y = __builtin_amdgcn_mfma_f32_16x16x32_f16(a[kc], bfr, y, 0, 0, 0);
        }
        #pragma unroll
        for(int r = 0; r < 4; r++){
            int row = rb + w * 16 + quad * 4 + r;
            int col = nt * 16 + l15;
            out[row * 64 + col] = y[r] + b4f[col] + x[row * 64 + col];
        }
    }
}

extern "C" void kernel_launch(void* const* d_in, const int* in_sizes, int n_in,
                              void* d_out, int out_size, void* d_ws, size_t ws_size,
                              hipStream_t stream){
    (void)in_sizes; (void)n_in; (void)out_size; (void)ws_size;
    const float* x  = (const float*)d_in[0];
    const float* w1 = (const float*)d_in[1];
    const float* w2 = (const float*)d_in[2];
    const float* w3 = (const float*)d_in[3];
    const float* w4 = (const float*)d_in[4];
    const float* b1 = (const float*)d_in[5];
    const float* b2 = (const float*)d_in[6];
    const float* b3 = (const float*)d_in[7];
    const float* b4 = (const float*)d_in[8];
    const float* gm = (const float*)d_in[9];
    const float* bt = (const float*)d_in[10];
    char* ws = (char*)d_ws;
    f16* Q    = (f16*)(ws);
    f16* Kx   = (f16*)(ws + (size_t)(2u << 20));
    f16* Vt   = (f16*)(ws + (size_t)(4u << 20));
    float* part = (float*)(ws + (size_t)(6u << 20));                         // 256 x 128 f32 = 128KB
    f16* Oph  = (f16*)(ws + (size_t)(8u << 20));                             // 8 x 2MB (f16, normalized)
    float* lwp = (float*)(ws + (size_t)(24u << 20));                         // 8 x 64KB

    hipLaunchKernelGGL(k_bnstats, dim3(256),  dim3(256), 0, stream, x, part);
    hipLaunchKernelGGL(k_qkv,     dim3(256),  dim3(256), 0, stream, x, w1, w2, w3, b1, b2, b3, gm, bt, part, Q, Kx, Vt);
    hipLaunchKernelGGL(k_attn,    dim3(1024), dim3(256), 0, stream, Q, Kx, Vt, Oph, lwp);
    hipLaunchKernelGGL(k_merge,   dim3(256),  dim3(256), 0, stream, Oph, lwp, w4, b4, x, (float*)d_out);
}